// Round 2
// baseline (1445.091 us; speedup 1.0000x reference)
//
#include <hip/hip_runtime.h>

#define NB 64
#define NPER 131072
#define NTYPES 16
#define NITER 10
#define ACCV 1e-9

#define TB 256
#define TILES_PER_CHAIN (NPER / TB)          // 512
#define TILES_TOTAL (NB * TILES_PER_CHAIN)   // 32768
#define RED_BLOCKS 4096

struct LSState {
  double alpha;       // persistent alpha (frozen when done)
  double alpha_step;  // alpha to apply in this iteration's update
  int done;
  int do_update;
};

__device__ inline double wave_sum64(double v) {
  #pragma unroll
  for (int o = 32; o > 0; o >>= 1) v += __shfl_down(v, o, 64);
  return v;
}

__global__ void pc_init(LSState* st) {
  st->alpha = 0.0;
  st->alpha_step = 0.0;
  st->done = 0;
  st->do_update = 1;
}

// One pass over all bonds: accumulate S0..S4 for the quartic
// ctry(a) = S0 + S1 a + S2 a^2 + S3 a^3 + S4 a^4, with
//   c_i   = |dx_i|^2 - d_i^2,   C_i = c_i * dx_i
//   g_i   = lam_{i+1}-lam_i = 2(2C_i - C_{i-1} - C_{i+1})   (C zero-padded)
//   B_i   = -2 dx_i . g_i,      A_i = |g_i|^2
//   S0=Σc², S1=Σ2cB, S2=Σ(B²+2cA), S3=Σ2AB, S4=ΣA²;  ‖lam‖² = -S1/2
__global__ __launch_bounds__(TB) void pc_reduce(const float* __restrict__ x,
    const int* __restrict__ z, const float* __restrict__ d0,
    double* __restrict__ partials) {
  __shared__ float xs[(TB + 3) * 3];   // points s-1 .. s+257
  __shared__ int zs[TB + 3];
  __shared__ float d0s[NTYPES * NTYPES];
  __shared__ double redl[5][TB / 64];
  const int tid = threadIdx.x;
  if (tid < NTYPES * NTYPES) d0s[tid] = d0[tid];
  double s0 = 0, s1 = 0, s2 = 0, s3 = 0, s4 = 0;
  for (int tile = blockIdx.x; tile < TILES_TOTAL; tile += RED_BLOCKS) {
    const int b = tile / TILES_PER_CHAIN;
    const int s = (tile % TILES_PER_CHAIN) * TB;   // first bond of tile
    const int base = b * NPER;
    __syncthreads();   // protect LDS reuse across tiles (also covers d0s 1st time)
    const int gf0 = (base + s - 1) * 3;
    const int lo = base * 3, hi = (base + NPER) * 3;
    for (int f = tid; f < (TB + 3) * 3; f += TB) {
      const int g = gf0 + f;
      xs[f] = (g >= lo && g < hi) ? x[g] : 0.f;
    }
    for (int idx = tid; idx < TB + 3; idx += TB) {
      const int p = s - 1 + idx;
      zs[idx] = (p >= 0 && p < NPER) ? z[base + p] : 0;
    }
    __syncthreads();
    const int i = s + tid;   // bond index within chain
    if (i <= NPER - 2) {
      float C[3][3];
      float dxc[3] = {0.f, 0.f, 0.f};
      float cc = 0.f;
      #pragma unroll
      for (int k = 0; k < 3; ++k) {
        const int j = i - 1 + k;
        if (j >= 0 && j <= NPER - 2) {
          const int lp = j - (s - 1);
          const int l = lp * 3;
          const float dxv = xs[l + 3] - xs[l + 0];
          const float dyv = xs[l + 4] - xs[l + 1];
          const float dzv = xs[l + 5] - xs[l + 2];
          const float dd = d0s[zs[lp] * NTYPES + zs[lp + 1]];
          const float c = dxv * dxv + dyv * dyv + dzv * dzv - dd * dd;
          C[k][0] = c * dxv; C[k][1] = c * dyv; C[k][2] = c * dzv;
          if (k == 1) { dxc[0] = dxv; dxc[1] = dyv; dxc[2] = dzv; cc = c; }
        } else {
          C[k][0] = 0.f; C[k][1] = 0.f; C[k][2] = 0.f;
        }
      }
      const float gx = 2.f * (2.f * C[1][0] - C[0][0] - C[2][0]);
      const float gy = 2.f * (2.f * C[1][1] - C[0][1] - C[2][1]);
      const float gz = 2.f * (2.f * C[1][2] - C[0][2] - C[2][2]);
      const float A = gx * gx + gy * gy + gz * gz;
      const float Bv = -2.f * (dxc[0] * gx + dxc[1] * gy + dxc[2] * gz);
      s0 += (double)cc * (double)cc;
      s1 += 2.0 * (double)cc * (double)Bv;
      s2 += (double)Bv * (double)Bv + 2.0 * (double)cc * (double)A;
      s3 += 2.0 * (double)A * (double)Bv;
      s4 += (double)A * (double)A;
    }
  }
  const int wave = tid >> 6, lane = tid & 63;
  double v[5] = {s0, s1, s2, s3, s4};
  #pragma unroll
  for (int k = 0; k < 5; ++k) {
    const double w = wave_sum64(v[k]);
    if (lane == 0) redl[k][wave] = w;
  }
  __syncthreads();
  if (tid == 0) {
    #pragma unroll
    for (int k = 0; k < 5; ++k)
      partials[k * RED_BLOCKS + blockIdx.x] =
          redl[k][0] + redl[k][1] + redl[k][2] + redl[k][3];
  }
}

// Final reduction of partials + the entire backtracking line search on the
// quartic polynomial; updates device-side alpha/done state.
__global__ __launch_bounds__(256) void pc_linesearch(
    const double* __restrict__ partials, LSState* st, int iter) {
  __shared__ double redl[5][4];
  const int tid = threadIdx.x;
  double v[5] = {0, 0, 0, 0, 0};
  for (int i = tid; i < RED_BLOCKS; i += 256) {
    #pragma unroll
    for (int k = 0; k < 5; ++k) v[k] += partials[k * RED_BLOCKS + i];
  }
  const int wave = tid >> 6, lane = tid & 63;
  #pragma unroll
  for (int k = 0; k < 5; ++k) {
    const double w = wave_sum64(v[k]);
    if (lane == 0) redl[k][wave] = w;
  }
  __syncthreads();
  if (tid == 0) {
    double S[5];
    #pragma unroll
    for (int k = 0; k < 5; ++k)
      S[k] = redl[k][0] + redl[k][1] + redl[k][2] + redl[k][3];
    const double cnorm = S[0];
    // ||lam||^2 == -S1/2 exactly (summation-by-parts identity)
    double alpha = (iter == 0) ? 1.0 / sqrt(-0.5 * S[1]) : st->alpha;
    int lsiter = 0;
    double ctry;
    for (;;) {
      ctry = S[0] + alpha * (S[1] + alpha * (S[2] + alpha * (S[3] + alpha * S[4])));
      if (ctry < cnorm) break;     // ok -> keep alpha
      alpha *= 0.5;
      if (++lsiter > 10) break;    // matches while_loop exit semantics
    }
    if (lsiter == 0 && ctry > ACCV) alpha *= 1.5;
    const int done_prev = st->done;
    st->alpha_step = alpha;
    st->do_update = done_prev ? 0 : 1;
    if (!done_prev) st->alpha = alpha;
    st->done = done_prev | ((ctry < ACCV) ? 1 : 0);
  }
}

// x[p] -= alpha * lam_p, lam_p = 2*(C_{p-1} - C_p); recompute C in-tile.
__global__ __launch_bounds__(TB) void pc_update(float* __restrict__ x,
    const int* __restrict__ z, const float* __restrict__ d0,
    const LSState* __restrict__ st) {
  if (!st->do_update) return;   // uniform across all threads
  __shared__ float xs[(TB + 2) * 3];   // points s-1 .. s+256
  __shared__ int zs[TB + 2];
  __shared__ float d0s[NTYPES * NTYPES];
  const int tid = threadIdx.x;
  const int tile = blockIdx.x;
  const int b = tile / TILES_PER_CHAIN;
  const int s = (tile % TILES_PER_CHAIN) * TB;   // first point of tile
  const int base = b * NPER;
  if (tid < NTYPES * NTYPES) d0s[tid] = d0[tid];
  const int gf0 = (base + s - 1) * 3;
  const int lo = base * 3, hi = (base + NPER) * 3;
  for (int f = tid; f < (TB + 2) * 3; f += TB) {
    const int g = gf0 + f;
    xs[f] = (g >= lo && g < hi) ? x[g] : 0.f;
  }
  for (int idx = tid; idx < TB + 2; idx += TB) {
    const int p = s - 1 + idx;
    zs[idx] = (p >= 0 && p < NPER) ? z[base + p] : 0;
  }
  __syncthreads();
  const int p = s + tid;   // point index
  const float alpha = (float)st->alpha_step;
  float Cm[3], Cc[3];
  #pragma unroll
  for (int k = 0; k < 2; ++k) {
    const int j = p - 1 + k;
    float* Co = (k == 0) ? Cm : Cc;
    if (j >= 0 && j <= NPER - 2) {
      const int lp = j - (s - 1);
      const int l = lp * 3;
      const float dxv = xs[l + 3] - xs[l + 0];
      const float dyv = xs[l + 4] - xs[l + 1];
      const float dzv = xs[l + 5] - xs[l + 2];
      const float dd = d0s[zs[lp] * NTYPES + zs[lp + 1]];
      const float c = dxv * dxv + dyv * dyv + dzv * dzv - dd * dd;
      Co[0] = c * dxv; Co[1] = c * dyv; Co[2] = c * dzv;
    } else {
      Co[0] = 0.f; Co[1] = 0.f; Co[2] = 0.f;
    }
  }
  const float lx = 2.f * (Cm[0] - Cc[0]);
  const float ly = 2.f * (Cm[1] - Cc[1]);
  const float lz = 2.f * (Cm[2] - Cc[2]);
  const int li = (tid + 1) * 3;
  const int g = (base + p) * 3;
  x[g + 0] = xs[li + 0] - alpha * lx;
  x[g + 1] = xs[li + 1] - alpha * ly;
  x[g + 2] = xs[li + 2] - alpha * lz;
}

extern "C" void kernel_launch(void* const* d_in, const int* in_sizes, int n_in,
                              void* d_out, int out_size, void* d_ws, size_t ws_size,
                              hipStream_t stream) {
  const float* d0 = (const float*)d_in[1];
  const int* z = (const int*)d_in[3];          // d_in[2] = batch (unused)
  float* x = (float*)d_out;
  LSState* st = (LSState*)d_ws;
  double* partials = (double*)((char*)d_ws + 256);

  hipMemcpyAsync(d_out, d_in[0], (size_t)NB * NPER * 3 * sizeof(float),
                 hipMemcpyDeviceToDevice, stream);
  pc_init<<<1, 1, 0, stream>>>(st);
  for (int j = 0; j < NITER; ++j) {
    pc_reduce<<<RED_BLOCKS, TB, 0, stream>>>(x, z, d0, partials);
    pc_linesearch<<<1, 256, 0, stream>>>(partials, st, j);
    pc_update<<<TILES_TOTAL, TB, 0, stream>>>(x, z, d0, st);
  }
}